// Round 1
// baseline (397.016 us; speedup 1.0000x reference)
//
#include <hip/hip_runtime.h>
#include <hip/hip_bf16.h>
#include <cstdint>
#include <cstddef>

// Problem constants (from reference setup_inputs: x = (8192, 768) fp32)
#define GN 8192
#define GD 768
#define BM 128
#define BN 128
#define BK 32
#define CC 8                  // column chunks across grid.x
#define CHUNK (GN / CC)       // 1024 columns per WG
#define CTILES (CHUNK / BN)   // 8 column tiles per chunk
#define KSTEPS (GD / BK)      // 24

typedef __attribute__((ext_vector_type(8))) short bf16x8;  // 8 bf16 = 4 VGPRs
typedef __attribute__((ext_vector_type(4))) float f32x4;

typedef __attribute__((address_space(1))) const unsigned int gu32;
typedef __attribute__((address_space(3))) unsigned int lu32;

__device__ __forceinline__ void gl2lds16(const void* g, void* l) {
    // async global->LDS, 16B per lane; LDS dest must be wave-uniform base + lane*16
    __builtin_amdgcn_global_load_lds((gu32*)g, (lu32*)l, 16, 0, 0);
}

// ---------------- Kernel 1: bf16 cast + row sum-of-squares ----------------
__global__ __launch_bounds__(256) void prep_kernel(const float* __restrict__ x,
                                                   __hip_bfloat16* __restrict__ xb,
                                                   float* __restrict__ sq) {
    const int row = blockIdx.x;
    const float* xr = x + (size_t)row * GD;
    __hip_bfloat16* xbr = xb + (size_t)row * GD;
    const int t = threadIdx.x;
    float s = 0.f;
#pragma unroll
    for (int i = 0; i < GD / 256; ++i) {
        float v = xr[t + i * 256];
        s += v * v;
        xbr[t + i * 256] = __float2bfloat16(v);
    }
#pragma unroll
    for (int off = 1; off < 64; off <<= 1) s += __shfl_xor(s, off);
    __shared__ float ls[4];
    if ((t & 63) == 0) ls[t >> 6] = s;
    __syncthreads();
    if (t == 0) sq[row] = ls[0] + ls[1] + ls[2] + ls[3];
}

// ------- Kernel 2: fused bf16 MFMA GEMM (x @ x^T) + online softmax-entropy -------
// grid = (CC, GN/BM). Each WG: 128 rows x 1024 cols, K = 768.
// Waves 2x2; each wave owns a 64x64 quadrant = 4x4 grid of 16x16x32 MFMA tiles.
// C/D layout: col = lane&15, row = (lane>>4)*4 + reg.
__global__ __launch_bounds__(256) void gemm_entropy(const __hip_bfloat16* __restrict__ xb,
                                                    const float* __restrict__ sq,
                                                    const float* __restrict__ taup,
                                                    float* __restrict__ parts) {
    __shared__ __align__(16) __hip_bfloat16 As[BM * BK];  // [row][k], 8 KB
    __shared__ __align__(16) __hip_bfloat16 Bs[BN * BK];  // [col][k], 8 KB
    __shared__ float mrg[BM][3];

    const int tid = threadIdx.x;
    const int lane = tid & 63;
    const int w = tid >> 6;
    const int wm = w >> 1, wn = w & 1;
    const int quad = lane >> 4, cl = lane & 15;
    const int row_base = blockIdx.y * BM;
    const int chunk = blockIdx.x;
    const int chunk_base = chunk * CHUNK;
    const float tau = *taup;

    // rows owned by this lane (16 of them) + their sq
    int rowg[16];
    float sqr[16];
#pragma unroll
    for (int ti = 0; ti < 4; ++ti)
#pragma unroll
        for (int rg = 0; rg < 4; ++rg) {
            int r = row_base + wm * 64 + ti * 16 + quad * 4 + rg;
            rowg[ti * 4 + rg] = r;
            sqr[ti * 4 + rg] = sq[r];
        }

    // running online-softmax state per row (replicated across the 16 lanes of a quad)
    float rm[16], rs[16], rt[16];
#pragma unroll
    for (int i = 0; i < 16; ++i) { rm[i] = -1e30f; rs[i] = 0.f; rt[i] = 0.f; }

    // staging: thread t stages 16B at LDS offset t*16 (rows t/4, k-cols (t&3)*8)
    const int arow = tid >> 2;
    const int acol = (tid & 3) * 8;
    const __hip_bfloat16* aBase = xb + (size_t)(row_base + arow) * GD + acol;
    char* aLds = (char*)As + tid * 16;
    char* bLds = (char*)Bs + tid * 16;

    for (int ct = 0; ct < CTILES; ++ct) {
        const int col_base = chunk_base + ct * BN;
        const __hip_bfloat16* bBase = xb + (size_t)(col_base + arow) * GD + acol;
        f32x4 acc[4][4];
#pragma unroll
        for (int i = 0; i < 4; ++i)
#pragma unroll
            for (int j = 0; j < 4; ++j) acc[i][j] = (f32x4){0.f, 0.f, 0.f, 0.f};

        for (int kk = 0; kk < KSTEPS; ++kk) {
            const int k0 = kk * BK;
            __syncthreads();  // prior iter's ds_reads done before overwrite
            gl2lds16(aBase + k0, aLds);
            gl2lds16(aBase + (size_t)64 * GD + k0, aLds + 4096);
            gl2lds16(bBase + k0, bLds);
            gl2lds16(bBase + (size_t)64 * GD + k0, bLds + 4096);
            __syncthreads();  // drains vmcnt -> staged data visible

            bf16x8 af[4], bfr[4];
#pragma unroll
            for (int ti = 0; ti < 4; ++ti)
                af[ti] = *(const bf16x8*)(As + (wm * 64 + ti * 16 + cl) * BK + quad * 8);
#pragma unroll
            for (int tj = 0; tj < 4; ++tj)
                bfr[tj] = *(const bf16x8*)(Bs + (wn * 64 + tj * 16 + cl) * BK + quad * 8);
#pragma unroll
            for (int ti = 0; ti < 4; ++ti)
#pragma unroll
                for (int tj = 0; tj < 4; ++tj)
                    acc[ti][tj] = __builtin_amdgcn_mfma_f32_16x16x32_bf16(
                        af[ti], bfr[tj], acc[ti][tj], 0, 0, 0);
        }

        // ---- epilogue: sim -> per-row (max, S, T) over this 128-col tile ----
        int colg[4];
        float sqc[4];
#pragma unroll
        for (int tj = 0; tj < 4; ++tj) {
            colg[tj] = col_base + wn * 64 + tj * 16 + cl;
            sqc[tj] = sq[colg[tj]];
        }
#pragma unroll
        for (int ti = 0; ti < 4; ++ti) {
#pragma unroll
            for (int rg = 0; rg < 4; ++rg) {
                const int idx = ti * 4 + rg;
                float v[4];
#pragma unroll
                for (int tj = 0; tj < 4; ++tj) {
                    float pen = (rowg[idx] == colg[tj]) ? 100.f : 0.f;
                    v[tj] = tau * (2.f * acc[ti][tj][rg] - sqr[idx] - sqc[tj] - pen);
                }
                float mt = fmaxf(fmaxf(v[0], v[1]), fmaxf(v[2], v[3]));
#pragma unroll
                for (int mk = 1; mk < 16; mk <<= 1) mt = fmaxf(mt, __shfl_xor(mt, mk));
                float s = 0.f, t = 0.f;
#pragma unroll
                for (int tj = 0; tj < 4; ++tj) {
                    float d = v[tj] - mt;
                    float e = __expf(d);
                    s += e;
                    t += e * d;
                }
#pragma unroll
                for (int mk = 1; mk < 16; mk <<= 1) {
                    s += __shfl_xor(s, mk);
                    t += __shfl_xor(t, mk);
                }
                // merge tile (mt,s,t) into running (rm,rs,rt)
                float mo = rm[idx];
                float mn = fmaxf(mo, mt);
                float ea = __expf(mo - mn), eb = __expf(mt - mn);
                float so = rs[idx];
                rs[idx] = so * ea + s * eb;
                rt[idx] = (rt[idx] + (mo - mn) * so) * ea + (t + (mt - mn) * s) * eb;
                rm[idx] = mn;
            }
        }
    }

    // ---- cross-wave_n merge (wn=0 half-columns + wn=1 half-columns) ----
    __syncthreads();
    if (wn == 0 && cl == 0) {
#pragma unroll
        for (int i = 0; i < 16; ++i) {
            int rl = wm * 64 + (i >> 2) * 16 + quad * 4 + (i & 3);
            mrg[rl][0] = rm[i];
            mrg[rl][1] = rs[i];
            mrg[rl][2] = rt[i];
        }
    }
    __syncthreads();
    if (wn == 1 && cl == 0) {
#pragma unroll
        for (int i = 0; i < 16; ++i) {
            int rl = wm * 64 + (i >> 2) * 16 + quad * 4 + (i & 3);
            float mo = mrg[rl][0], so = mrg[rl][1], to = mrg[rl][2];
            float mn = fmaxf(mo, rm[i]);
            float ea = __expf(mo - mn), eb = __expf(rm[i] - mn);
            float S = so * ea + rs[i] * eb;
            float T = (to + (mo - mn) * so) * ea + (rt[i] + (rm[i] - mn) * rs[i]) * eb;
            float* p = parts + ((size_t)rowg[i] * CC + chunk) * 3;
            p[0] = mn;
            p[1] = S;
            p[2] = T;
        }
    }
}

// ---------------- Kernel 3: combine chunk partials -> row entropy -> block sums ----------------
__global__ __launch_bounds__(256) void row_entropy(const float* __restrict__ parts,
                                                   float* __restrict__ bsums) {
    const int row = blockIdx.x * 256 + threadIdx.x;
    const float* p = parts + (size_t)row * CC * 3;
    float m = -1e30f, S = 0.f, T = 0.f;
#pragma unroll
    for (int c = 0; c < CC; ++c) {
        float mc = p[c * 3 + 0], Sc = p[c * 3 + 1], Tc = p[c * 3 + 2];
        float mn = fmaxf(m, mc);
        float ea = __expf(m - mn), eb = __expf(mc - mn);
        float Sn = S * ea + Sc * eb;
        T = (T + (m - mn) * S) * ea + (Tc + (mc - mn) * Sc) * eb;
        S = Sn;
        m = mn;
    }
    float ent = __logf(S) - T / S;  // entropy_i = log S - T/S
#pragma unroll
    for (int off = 1; off < 64; off <<= 1) ent += __shfl_xor(ent, off);
    __shared__ float ls[4];
    if ((threadIdx.x & 63) == 0) ls[threadIdx.x >> 6] = ent;
    __syncthreads();
    if (threadIdx.x == 0) bsums[blockIdx.x] = ls[0] + ls[1] + ls[2] + ls[3];
}

// ---------------- Kernel 4: final scalar ----------------
__global__ __launch_bounds__(64) void finalize(const float* __restrict__ bsums,
                                               const float* __restrict__ coefp,
                                               float* __restrict__ out) {
    const int t = threadIdx.x;
    float v = (t < GN / 256) ? bsums[t] : 0.f;
#pragma unroll
    for (int off = 1; off < 64; off <<= 1) v += __shfl_xor(v, off);
    if (t == 0) out[0] = coefp[0] * v / (float)GN;
}

extern "C" void kernel_launch(void* const* d_in, const int* in_sizes, int n_in,
                              void* d_out, int out_size, void* d_ws, size_t ws_size,
                              hipStream_t stream) {
    const float* x = (const float*)d_in[0];      // 8192*768 fp32
    const float* coefp = (const float*)d_in[1];  // scalar
    const float* taup = (const float*)d_in[2];   // scalar
    float* out = (float*)d_out;

    char* ws = (char*)d_ws;
    __hip_bfloat16* xb = (__hip_bfloat16*)ws;          // 12,582,912 B
    float* sq = (float*)(ws + 12582912);               // 32,768 B
    float* parts = (float*)(ws + 12615680);            // 8192*8*3*4 = 786,432 B
    float* bsums = (float*)(ws + 13402112);            // 128 B

    prep_kernel<<<GN, 256, 0, stream>>>(x, xb, sq);
    gemm_entropy<<<dim3(CC, GN / BM), 256, 0, stream>>>(xb, sq, taup, parts);
    row_entropy<<<GN / 256, 256, 0, stream>>>(parts, bsums);
    finalize<<<1, 64, 0, stream>>>(bsums, coefp, out);
}

// Round 2
// 170.624 us; speedup vs baseline: 2.3269x; 2.3269x over previous
//
#include <hip/hip_runtime.h>
#include <hip/hip_bf16.h>
#include <cstdint>
#include <cstddef>

// Problem constants (from reference setup_inputs: x = (8192, 768) fp32)
#define GN 8192
#define GD 768
#define NB 64            // 128-row blocks
#define NTILE 2080       // NB*(NB+1)/2 triangular tiles
// legacy (fallback path) constants
#define BM 128
#define BN 128
#define BK 32
#define CC 8
#define CHUNK (GN / CC)
#define CTILES (CHUNK / BN)
#define KSTEPS (GD / BK)

typedef __attribute__((ext_vector_type(8))) short bf16x8;  // 8 bf16 = 4 VGPRs
typedef __attribute__((ext_vector_type(4))) float f32x4;

typedef __attribute__((address_space(1))) const unsigned int gu32;
typedef __attribute__((address_space(3))) unsigned int lu32;

__device__ __forceinline__ void gl2lds16(const void* g, void* l) {
    // async global->LDS, 16B per lane; LDS dest is wave-uniform base + lane*16
    __builtin_amdgcn_global_load_lds((gu32*)g, (lu32*)l, 16, 0, 0);
}

// swizzled LDS byte offset for (row, 16B-kblock) with 64B rows paired into
// 128B super-rows; kblock XOR'd by (superrow&7) -> 2-way-max bank aliasing
__device__ __forceinline__ int swz(int r, int kb) {
    return ((r >> 1) << 7) + (((((r & 1) << 2) | kb) ^ ((r >> 1) & 7)) << 4);
}

// ---------------- Kernel 1: bf16 cast + row sum-of-squares ----------------
__global__ __launch_bounds__(256) void prep_kernel(const float* __restrict__ x,
                                                   __hip_bfloat16* __restrict__ xb,
                                                   float* __restrict__ sq) {
    const int row = blockIdx.x;
    const float* xr = x + (size_t)row * GD;
    __hip_bfloat16* xbr = xb + (size_t)row * GD;
    const int t = threadIdx.x;
    float s = 0.f;
#pragma unroll
    for (int i = 0; i < GD / 256; ++i) {
        float v = xr[t + i * 256];
        s += v * v;
        xbr[t + i * 256] = __float2bfloat16(v);
    }
#pragma unroll
    for (int off = 1; off < 64; off <<= 1) s += __shfl_xor(s, off);
    __shared__ float ls[4];
    if ((t & 63) == 0) ls[t >> 6] = s;
    __syncthreads();
    if (t == 0) sq[row] = ls[0] + ls[1] + ls[2] + ls[3];
}

// ------- Kernel 2 (primary): symmetric triangular tile GEMM + entropy partials -------
// One 128x128 tile (I,J), J<=I, per WG. 4 waves stacked in M (32 rows x 128 cols
// each). Direct pass -> partial (m,S,T) for rows of block I at slot J; transposed
// pass (I!=J) -> rows of block J at slot I. C/D: col=lane&15, row=(lane>>4)*4+reg.
__global__ __launch_bounds__(256, 3) void sym_gemm_entropy(
    const __hip_bfloat16* __restrict__ xb, const float* __restrict__ sq,
    const float* __restrict__ taup, float* __restrict__ pm,
    float* __restrict__ ps, float* __restrict__ pt) {
    __shared__ __align__(16) char As[8192];
    __shared__ __align__(16) char Bs[8192];
    __shared__ float tmrg[128][4][3];

    const int tid = threadIdx.x;
    const int lane = tid & 63;
    const int w = tid >> 6;
    const int quad = lane >> 4, cl = lane & 15;

    const int b = blockIdx.x;
    int I = (int)((sqrtf(8.0f * (float)b + 1.0f) - 1.0f) * 0.5f);
    while ((I + 1) * (I + 2) / 2 <= b) ++I;
    while (I * (I + 1) / 2 > b) --I;
    const int J = b - I * (I + 1) / 2;
    const int row_base = I * 128;
    const int col_base = J * 128;
    const float tau = *taup;

    // staging decode: thread t stages LDS offset t*16; pick the global (row,kblock)
    // that belongs at that swizzled LDS slot
    const int bb = (tid & 7) ^ ((tid >> 3) & 7);
    const int sRow = ((tid >> 3) << 1) | (bb >> 2);  // 0..63
    const int sKb = bb & 3;
    const __hip_bfloat16* gA0 = xb + (size_t)(row_base + sRow) * GD + sKb * 8;
    const __hip_bfloat16* gA1 = gA0 + (size_t)64 * GD;
    const __hip_bfloat16* gB0 = xb + (size_t)(col_base + sRow) * GD + sKb * 8;
    const __hip_bfloat16* gB1 = gB0 + (size_t)64 * GD;
    char* lA0 = As + tid * 16;
    char* lA1 = As + 4096 + tid * 16;
    char* lB0 = Bs + tid * 16;
    char* lB1 = Bs + 4096 + tid * 16;

    int offA[2], offB[8];
#pragma unroll
    for (int ti = 0; ti < 2; ++ti) offA[ti] = swz(w * 32 + ti * 16 + cl, quad);
#pragma unroll
    for (int tj = 0; tj < 8; ++tj) offB[tj] = swz(tj * 16 + cl, quad);

    f32x4 acc[2][8];
#pragma unroll
    for (int i = 0; i < 2; ++i)
#pragma unroll
        for (int j = 0; j < 8; ++j) acc[i][j] = (f32x4){0.f, 0.f, 0.f, 0.f};

    for (int kk = 0; kk < GD / 32; ++kk) {
        const int k0 = kk * 32;
        __syncthreads();  // prior iter's ds_reads done before overwrite
        gl2lds16(gA0 + k0, lA0);
        gl2lds16(gA1 + k0, lA1);
        gl2lds16(gB0 + k0, lB0);
        gl2lds16(gB1 + k0, lB1);
        __syncthreads();  // staged data visible

        bf16x8 af[2], bfv[8];
#pragma unroll
        for (int ti = 0; ti < 2; ++ti) af[ti] = *(const bf16x8*)(As + offA[ti]);
#pragma unroll
        for (int tj = 0; tj < 8; ++tj) bfv[tj] = *(const bf16x8*)(Bs + offB[tj]);
#pragma unroll
        for (int ti = 0; ti < 2; ++ti)
#pragma unroll
            for (int tj = 0; tj < 8; ++tj)
                acc[ti][tj] = __builtin_amdgcn_mfma_f32_16x16x32_bf16(
                    af[ti], bfv[tj], acc[ti][tj], 0, 0, 0);
    }

    // per-lane metadata
    float sqr[8];
    int rowg[8];
#pragma unroll
    for (int ti = 0; ti < 2; ++ti)
#pragma unroll
        for (int rg = 0; rg < 4; ++rg) {
            int r = row_base + w * 32 + ti * 16 + quad * 4 + rg;
            rowg[ti * 4 + rg] = r;
            sqr[ti * 4 + rg] = sq[r];
        }
    float sqc[8];
    int colg[8];
#pragma unroll
    for (int tj = 0; tj < 8; ++tj) {
        int c = col_base + tj * 16 + cl;
        colg[tj] = c;
        sqc[tj] = sq[c];
    }

    // ---- direct pass: one (m,S,T) per row of block I over J's 128 cols ----
#pragma unroll
    for (int ti = 0; ti < 2; ++ti)
#pragma unroll
        for (int rg = 0; rg < 4; ++rg) {
            const int idx = ti * 4 + rg;
            float vv[8];
            float mloc = -1e30f;
#pragma unroll
            for (int tj = 0; tj < 8; ++tj) {
                float pen = (rowg[idx] == colg[tj]) ? 100.f : 0.f;
                float v = tau * (2.f * acc[ti][tj][rg] - sqr[idx] - sqc[tj] - pen);
                vv[tj] = v;
                mloc = fmaxf(mloc, v);
            }
#pragma unroll
            for (int mk = 1; mk < 16; mk <<= 1) mloc = fmaxf(mloc, __shfl_xor(mloc, mk));
            float s = 0.f, t = 0.f;
#pragma unroll
            for (int tj = 0; tj < 8; ++tj) {
                float d = vv[tj] - mloc;
                float e = __expf(d);
                s += e;
                t += e * d;
            }
#pragma unroll
            for (int mk = 1; mk < 16; mk <<= 1) {
                s += __shfl_xor(s, mk);
                t += __shfl_xor(t, mk);
            }
            if (cl == 0) {
                int r = rowg[idx];
                pm[(size_t)J * GN + r] = mloc;
                ps[(size_t)J * GN + r] = s;
                pt[(size_t)J * GN + r] = t;
            }
        }

    // ---- transposed pass (off-diagonal tiles): rows of block J over I's rows ----
    if (I != J) {  // block-uniform branch
#pragma unroll
        for (int tj = 0; tj < 8; ++tj) {
            float vv[8];
            float mloc = -1e30f;
#pragma unroll
            for (int ti = 0; ti < 2; ++ti)
#pragma unroll
                for (int rg = 0; rg < 4; ++rg) {
                    float v = tau * (2.f * acc[ti][tj][rg] - sqr[ti * 4 + rg] - sqc[tj]);
                    vv[ti * 4 + rg] = v;
                    mloc = fmaxf(mloc, v);
                }
            mloc = fmaxf(mloc, __shfl_xor(mloc, 16));
            mloc = fmaxf(mloc, __shfl_xor(mloc, 32));
            float s = 0.f, t = 0.f;
#pragma unroll
            for (int k = 0; k < 8; ++k) {
                float d = vv[k] - mloc;
                float e = __expf(d);
                s += e;
                t += e * d;
            }
            s += __shfl_xor(s, 16);
            t += __shfl_xor(t, 16);
            s += __shfl_xor(s, 32);
            t += __shfl_xor(t, 32);
            if (quad == 0) {
                int c = tj * 16 + cl;
                tmrg[c][w][0] = mloc;
                tmrg[c][w][1] = s;
                tmrg[c][w][2] = t;
            }
        }
        __syncthreads();
        if (tid < 128) {
            float m = tmrg[tid][0][0], S = tmrg[tid][0][1], T = tmrg[tid][0][2];
#pragma unroll
            for (int ww = 1; ww < 4; ++ww) {
                float mc = tmrg[tid][ww][0], Sc = tmrg[tid][ww][1], Tc = tmrg[tid][ww][2];
                float mn = fmaxf(m, mc);
                float ea = __expf(m - mn), eb = __expf(mc - mn);
                T = (T + (m - mn) * S) * ea + (Tc + (mc - mn) * Sc) * eb;
                S = S * ea + Sc * eb;
                m = mn;
            }
            int c = col_base + tid;
            pm[(size_t)I * GN + c] = m;
            ps[(size_t)I * GN + c] = S;
            pt[(size_t)I * GN + c] = T;
        }
    }
}

// ---------------- Kernel 3 (primary): combine 64 slots -> row entropy -> block sums ----------------
__global__ __launch_bounds__(256) void combine(const float* __restrict__ pm,
                                               const float* __restrict__ ps,
                                               const float* __restrict__ pt,
                                               float* __restrict__ bsums) {
    const int row = blockIdx.x * 256 + threadIdx.x;
    float m = -1e30f, S = 0.f, T = 0.f;
    for (int c = 0; c < NB; ++c) {
        float mc = pm[(size_t)c * GN + row];
        float Sc = ps[(size_t)c * GN + row];
        float Tc = pt[(size_t)c * GN + row];
        float mn = fmaxf(m, mc);
        float ea = __expf(m - mn), eb = __expf(mc - mn);
        T = (T + (m - mn) * S) * ea + (Tc + (mc - mn) * Sc) * eb;
        S = S * ea + Sc * eb;
        m = mn;
    }
    float ent = __logf(S) - T / S;
#pragma unroll
    for (int off = 1; off < 64; off <<= 1) ent += __shfl_xor(ent, off);
    __shared__ float ls[4];
    if ((threadIdx.x & 63) == 0) ls[threadIdx.x >> 6] = ent;
    __syncthreads();
    if (threadIdx.x == 0) bsums[blockIdx.x] = ls[0] + ls[1] + ls[2] + ls[3];
}

// ---------------- Kernel 4: final scalar ----------------
__global__ __launch_bounds__(64) void finalize(const float* __restrict__ bsums,
                                               const float* __restrict__ coefp,
                                               float* __restrict__ out) {
    const int t = threadIdx.x;
    float v = (t < GN / 256) ? bsums[t] : 0.f;
#pragma unroll
    for (int off = 1; off < 64; off <<= 1) v += __shfl_xor(v, off);
    if (t == 0) out[0] = coefp[0] * v / (float)GN;
}

// ================= fallback path (R1, known-good, 13.4 MB ws) =================
__global__ __launch_bounds__(256) void gemm_entropy(const __hip_bfloat16* __restrict__ xb,
                                                    const float* __restrict__ sq,
                                                    const float* __restrict__ taup,
                                                    float* __restrict__ parts) {
    __shared__ __align__(16) __hip_bfloat16 Asf[BM * BK];
    __shared__ __align__(16) __hip_bfloat16 Bsf[BN * BK];
    __shared__ float mrg[BM][3];

    const int tid = threadIdx.x;
    const int lane = tid & 63;
    const int w = tid >> 6;
    const int wm = w >> 1, wn = w & 1;
    const int quad = lane >> 4, cl = lane & 15;
    const int row_base = blockIdx.y * BM;
    const int chunk = blockIdx.x;
    const int chunk_base = chunk * CHUNK;
    const float tau = *taup;

    int rowg[16];
    float sqr[16];
#pragma unroll
    for (int ti = 0; ti < 4; ++ti)
#pragma unroll
        for (int rg = 0; rg < 4; ++rg) {
            int r = row_base + wm * 64 + ti * 16 + quad * 4 + rg;
            rowg[ti * 4 + rg] = r;
            sqr[ti * 4 + rg] = sq[r];
        }

    float rm[16], rs[16], rt[16];
#pragma unroll
    for (int i = 0; i < 16; ++i) { rm[i] = -1e30f; rs[i] = 0.f; rt[i] = 0.f; }

    const int arow = tid >> 2;
    const int acol = (tid & 3) * 8;
    const __hip_bfloat16* aBase = xb + (size_t)(row_base + arow) * GD + acol;
    char* aLds = (char*)Asf + tid * 16;
    char* bLds = (char*)Bsf + tid * 16;

    for (int ct = 0; ct < CTILES; ++ct) {
        const int col_base = chunk_base + ct * BN;
        const __hip_bfloat16* bBase = xb + (size_t)(col_base + arow) * GD + acol;
        f32x4 acc[4][4];
#pragma unroll
        for (int i = 0; i < 4; ++i)
#pragma unroll
            for (int j = 0; j < 4; ++j) acc[i][j] = (f32x4){0.f, 0.f, 0.f, 0.f};

        for (int kk = 0; kk < KSTEPS; ++kk) {
            const int k0 = kk * BK;
            __syncthreads();
            gl2lds16(aBase + k0, aLds);
            gl2lds16(aBase + (size_t)64 * GD + k0, aLds + 4096);
            gl2lds16(bBase + k0, bLds);
            gl2lds16(bBase + (size_t)64 * GD + k0, bLds + 4096);
            __syncthreads();

            bf16x8 af[4], bfr[4];
#pragma unroll
            for (int ti = 0; ti < 4; ++ti)
                af[ti] = *(const bf16x8*)(Asf + (wm * 64 + ti * 16 + cl) * BK + quad * 8);
#pragma unroll
            for (int tj = 0; tj < 4; ++tj)
                bfr[tj] = *(const bf16x8*)(Bsf + (wn * 64 + tj * 16 + cl) * BK + quad * 8);
#pragma unroll
            for (int ti = 0; ti < 4; ++ti)
#pragma unroll
                for (int tj = 0; tj < 4; ++tj)
                    acc[ti][tj] = __builtin_amdgcn_mfma_f32_16x16x32_bf16(
                        af[ti], bfr[tj], acc[ti][tj], 0, 0, 0);
        }

        int colg[4];
        float sqc[4];
#pragma unroll
        for (int tj = 0; tj < 4; ++tj) {
            colg[tj] = col_base + wn * 64 + tj * 16 + cl;
            sqc[tj] = sq[colg[tj]];
        }
#pragma unroll
        for (int ti = 0; ti < 4; ++ti) {
#pragma unroll
            for (int rg = 0; rg < 4; ++rg) {
                const int idx = ti * 4 + rg;
                float v[4];
#pragma unroll
                for (int tj = 0; tj < 4; ++tj) {
                    float pen = (rowg[idx] == colg[tj]) ? 100.f : 0.f;
                    v[tj] = tau * (2.f * acc[ti][tj][rg] - sqr[idx] - sqc[tj] - pen);
                }
                float mt = fmaxf(fmaxf(v[0], v[1]), fmaxf(v[2], v[3]));
#pragma unroll
                for (int mk = 1; mk < 16; mk <<= 1) mt = fmaxf(mt, __shfl_xor(mt, mk));
                float s = 0.f, t = 0.f;
#pragma unroll
                for (int tj = 0; tj < 4; ++tj) {
                    float d = v[tj] - mt;
                    float e = __expf(d);
                    s += e;
                    t += e * d;
                }
#pragma unroll
                for (int mk = 1; mk < 16; mk <<= 1) {
                    s += __shfl_xor(s, mk);
                    t += __shfl_xor(t, mk);
                }
                float mo = rm[idx];
                float mn = fmaxf(mo, mt);
                float ea = __expf(mo - mn), eb = __expf(mt - mn);
                float so = rs[idx];
                rs[idx] = so * ea + s * eb;
                rt[idx] = (rt[idx] + (mo - mn) * so) * ea + (t + (mt - mn) * s) * eb;
                rm[idx] = mn;
            }
        }
    }

    __syncthreads();
    if (wn == 0 && cl == 0) {
#pragma unroll
        for (int i = 0; i < 16; ++i) {
            int rl = wm * 64 + (i >> 2) * 16 + quad * 4 + (i & 3);
            mrg[rl][0] = rm[i];
            mrg[rl][1] = rs[i];
            mrg[rl][2] = rt[i];
        }
    }
    __syncthreads();
    if (wn == 1 && cl == 0) {
#pragma unroll
        for (int i = 0; i < 16; ++i) {
            int rl = wm * 64 + (i >> 2) * 16 + quad * 4 + (i & 3);
            float mo = mrg[rl][0], so = mrg[rl][1], to = mrg[rl][2];
            float mn = fmaxf(mo, rm[i]);
            float ea = __expf(mo - mn), eb = __expf(rm[i] - mn);
            float S = so * ea + rs[i] * eb;
            float T = (to + (mo - mn) * so) * ea + (rt[i] + (rm[i] - mn) * rs[i]) * eb;
            float* p = parts + ((size_t)rowg[i] * CC + chunk) * 3;
            p[0] = mn;
            p[1] = S;
            p[2] = T;
        }
    }
}

__global__ __launch_bounds__(256) void row_entropy(const float* __restrict__ parts,
                                                   float* __restrict__ bsums) {
    const int row = blockIdx.x * 256 + threadIdx.x;
    const float* p = parts + (size_t)row * CC * 3;
    float m = -1e30f, S = 0.f, T = 0.f;
#pragma unroll
    for (int c = 0; c < CC; ++c) {
        float mc = p[c * 3 + 0], Sc = p[c * 3 + 1], Tc = p[c * 3 + 2];
        float mn = fmaxf(m, mc);
        float ea = __expf(m - mn), eb = __expf(mc - mn);
        float Sn = S * ea + Sc * eb;
        T = (T + (m - mn) * S) * ea + (Tc + (mc - mn) * Sc) * eb;
        S = Sn;
        m = mn;
    }
    float ent = __logf(S) - T / S;
#pragma unroll
    for (int off = 1; off < 64; off <<= 1) ent += __shfl_xor(ent, off);
    __shared__ float ls[4];
    if ((threadIdx.x & 63) == 0) ls[threadIdx.x >> 6] = ent;
    __syncthreads();
    if (threadIdx.x == 0) bsums[blockIdx.x] = ls[0] + ls[1] + ls[2] + ls[3];
}

extern "C" void kernel_launch(void* const* d_in, const int* in_sizes, int n_in,
                              void* d_out, int out_size, void* d_ws, size_t ws_size,
                              hipStream_t stream) {
    const float* x = (const float*)d_in[0];      // 8192*768 fp32
    const float* coefp = (const float*)d_in[1];  // scalar
    const float* taup = (const float*)d_in[2];   // scalar
    float* out = (float*)d_out;

    char* ws = (char*)d_ws;
    __hip_bfloat16* xb = (__hip_bfloat16*)ws;  // 12,582,912 B
    float* sq = (float*)(ws + 12582912);       // 32,768 B -> 12,615,680

    const size_t need_sym = 12615680ull + 3ull * 2097152ull + 128ull;  // 18,907,264
    if (ws_size >= need_sym) {
        float* pm = (float*)(ws + 12615680);
        float* ps = (float*)(ws + 12615680 + 2097152);
        float* pt = (float*)(ws + 12615680 + 2 * 2097152);
        float* bsums = (float*)(ws + 12615680 + 3 * 2097152);  // 128 B

        prep_kernel<<<GN, 256, 0, stream>>>(x, xb, sq);
        sym_gemm_entropy<<<NTILE, 256, 0, stream>>>(xb, sq, taup, pm, ps, pt);
        combine<<<GN / 256, 256, 0, stream>>>(pm, ps, pt, bsums);
        finalize<<<1, 64, 0, stream>>>(bsums, coefp, out);
    } else {
        // R1 fallback (13,402,240 B ws)
        float* parts = (float*)(ws + 12615680);   // 786,432 B
        float* bsums = (float*)(ws + 13402112);   // 128 B
        prep_kernel<<<GN, 256, 0, stream>>>(x, xb, sq);
        gemm_entropy<<<dim3(CC, GN / BM), 256, 0, stream>>>(xb, sq, taup, parts);
        row_entropy<<<GN / 256, 256, 0, stream>>>(parts, bsums);
        finalize<<<1, 64, 0, stream>>>(bsums, coefp, out);
    }
}